// Round 1
// baseline (283.986 us; speedup 1.0000x reference)
//
#include <hip/hip_runtime.h>

#define S_LEN 2048
#define HDIM  512
#define KSZ   64
#define S_T   128     // seq rows per block
#define PH    16      // rows per phase
#define RING  80      // x window ring: 63 halo + 16 current + 1 spare
// 1/sqrt(2048)
#define INV_SQRT_S 0.02209708691207961f

struct Smem {
    float  lh[PH][HDIM];     // 32 KB: h-values of current 16-row phase
    float2 part[PH][33];     // stage-1 partials (+1 pad col for stage-2 bank spread)
    float2 stats[PH];        // (mean, rstd) per row
};

__device__ __forceinline__ void lds_barrier() {
    // LDS-only barrier: drain lgkmcnt but leave global loads/stores (vmcnt) in flight.
    asm volatile("s_waitcnt lgkmcnt(0)\n\ts_barrier" ::: "memory");
}

// Ring slot of block-local row r (r = s - s0) is (r + 64) % RING.
// Phase at sbase = s0 + 16p uses OFF = (64 + 16p) % RING, compile-time.
//
// Register budget (the point of this rewrite): ring 80 + hv 16 + xpa 8 + wv 12
// + ~8 misc ≈ 124 < 128 cap, so nothing gets demoted/rematerialized. The 64
// filter taps are STREAMED from L2 (w is 128 KB, L2-resident, shared by all
// blocks) through a triple-buffered 4-tap pipeline instead of occupying VGPRs.
template <int OFF, bool STAGE>
__device__ __forceinline__ void conv_phase(const float* __restrict__ xb,
                                           const float* __restrict__ wp,
                                           int sbase, int h,
                                           float (&ring)[RING], float (&xpa)[8],
                                           float (&hv)[PH], Smem* sm)
{
    // Refill first half: rows sbase..sbase+7 (prefetched into xpa last phase).
    // Second half (rows sbase+8..15) was loaded straight into the ring last phase.
#pragma unroll
    for (int j = 0; j < 8; ++j) ring[(OFF + j) % RING] = xpa[j];

    // Re-issue xpa prefetch: rows sbase+16..23, consumed at next phase's refill.
    if (STAGE) {
#pragma unroll
        for (int j = 0; j < 8; ++j)
            xpa[j] = xb[((sbase + PH + j) & (S_LEN - 1)) * HDIM + h];
    }

    // Accumulators (become h-values in the finish step).
#pragma unroll
    for (int j = 0; j < PH; ++j) hv[j] = 0.f;

    // w streamed from L2, triple-buffered in groups of 4 taps (256-cycle runway).
    float wv[3][4];
#pragma unroll
    for (int u = 0; u < 4; ++u) wv[0][u] = wp[u * HDIM];
#pragma unroll
    for (int u = 0; u < 4; ++u) wv[1][u] = wp[(4 + u) * HDIM];

#pragma unroll
    for (int kb = 0; kb < 16; ++kb) {
        if (kb < 14) {
#pragma unroll
            for (int u = 0; u < 4; ++u)
                wv[(kb + 2) % 3][u] = wp[((kb + 2) * 4 + u) * HDIM];
        }
#pragma unroll
        for (int u = 0; u < 4; ++u) {
            const int k = kb * 4 + u;
            const float wk = wv[kb % 3][u];
#pragma unroll
            for (int j = 0; j < PH; ++j)
                hv[j] = fmaf(wk, ring[(OFF + j - k + RING) % RING], hv[j]);
        }
    }

    // Prefetch rows sbase+24..31 straight into the ring slots that just died
    // (their old rows sbase-56..-49 were last read by taps k>=56 above).
    // Consumed at next phase's k-loop; the LN phase below covers the latency.
    if (STAGE) {
#pragma unroll
        for (int j = 0; j < 8; ++j)
            ring[(OFF + 24 + j) % RING] =
                xb[((sbase + 24 + j) & (S_LEN - 1)) * HDIM + h];
    }

    // Finish: scale + residual; stage h for the LN reduction.
#pragma unroll
    for (int j = 0; j < PH; ++j) {
        const float hval = fmaf(INV_SQRT_S, hv[j], ring[(OFF + j) % RING]);
        hv[j] = hval;
        sm->lh[j][h] = hval;
    }
}

__device__ __forceinline__ void ln_phase(int sbase, int h, const float (&hv)[PH],
                                         float gm, float bt, float* __restrict__ ob, Smem* sm)
{
    lds_barrier();   // all lh writes visible

    // Stage 1: 32 threads per row, strided conflict-free reads
    const int r = h >> 5, c = h & 31;
    float s1 = 0.f, q1 = 0.f;
#pragma unroll
    for (int m = 0; m < 16; ++m) {
        const float v = sm->lh[r][c + (m << 5)];
        s1 += v;
        q1 = fmaf(v, v, q1);
    }
    sm->part[r][c] = make_float2(s1, q1);
    lds_barrier();

    // Stage 2: wave 0 only, 4 lanes per row
    if (h < 64) {
        const int rr = h >> 2, q = h & 3;
        float ts = 0.f, tq = 0.f;
#pragma unroll
        for (int i = 0; i < 8; ++i) {
            const float2 p = sm->part[rr][q * 8 + i];
            ts += p.x; tq += p.y;
        }
        ts += __shfl_xor(ts, 1, 64); tq += __shfl_xor(tq, 1, 64);
        ts += __shfl_xor(ts, 2, 64); tq += __shfl_xor(tq, 2, 64);
        if (q == 0) {
            const float mean = ts * (1.0f / 512.0f);
            const float var  = fmaf(tq, 1.0f / 512.0f, -mean * mean);
            sm->stats[rr] = make_float2(mean, rsqrtf(var + 1e-12f));
        }
    }
    lds_barrier();

    // Epilogue: normalize from registers, broadcast stats reads, coalesced stores
#pragma unroll
    for (int j = 0; j < PH; ++j) {
        const float2 st = sm->stats[j];
        ob[(sbase + j) * HDIM + h] = fmaf((hv[j] - st.x) * st.y, gm, bt);
    }
}

__global__ __launch_bounds__(512, 2)
void fconv_ln(const float* __restrict__ x, const float* __restrict__ w,
              const float* __restrict__ gamma, const float* __restrict__ beta,
              float* __restrict__ out)
{
    __shared__ Smem sm;
    const int h  = threadIdx.x;          // channel
    const int b  = blockIdx.x >> 4;      // 16 tiles of 128 rows per batch
    const int s0 = (blockIdx.x & 15) * S_T;

    const float* xb = x   + (size_t)b * S_LEN * HDIM;
    float*       ob = out + (size_t)b * S_LEN * HDIM;
    const float* wp = w + h;             // w[k*HDIM + h] = wp[k*HDIM]
    const float gm = gamma[h], bt = beta[h];

    float ring[RING];
    // halo rows s0-63..s0-1 -> slots 1..63
#pragma unroll
    for (int d = 1; d <= 63; ++d)
        ring[64 - d] = xb[((s0 - d) & (S_LEN - 1)) * HDIM + h];
    ring[0] = 0.f;   // slot 0 first written by phase-1 refill, never read before
    // rows s0+8..15 straight into slots 72..79
#pragma unroll
    for (int j = 0; j < 8; ++j)
        ring[72 + j] = xb[(s0 + 8 + j) * HDIM + h];
    // rows s0..s0+7 into the register prefetch buffer
    float xpa[8];
#pragma unroll
    for (int j = 0; j < 8; ++j)
        xpa[j] = xb[(s0 + j) * HDIM + h];

    float hv[PH];
    // OFF sequence: (64 + 16p) % 80
    conv_phase<64, true >(xb, wp, s0 +   0, h, ring, xpa, hv, &sm); ln_phase(s0 +   0, h, hv, gm, bt, ob, &sm);
    conv_phase< 0, true >(xb, wp, s0 +  16, h, ring, xpa, hv, &sm); ln_phase(s0 +  16, h, hv, gm, bt, ob, &sm);
    conv_phase<16, true >(xb, wp, s0 +  32, h, ring, xpa, hv, &sm); ln_phase(s0 +  32, h, hv, gm, bt, ob, &sm);
    conv_phase<32, true >(xb, wp, s0 +  48, h, ring, xpa, hv, &sm); ln_phase(s0 +  48, h, hv, gm, bt, ob, &sm);
    conv_phase<48, true >(xb, wp, s0 +  64, h, ring, xpa, hv, &sm); ln_phase(s0 +  64, h, hv, gm, bt, ob, &sm);
    conv_phase<64, true >(xb, wp, s0 +  80, h, ring, xpa, hv, &sm); ln_phase(s0 +  80, h, hv, gm, bt, ob, &sm);
    conv_phase< 0, true >(xb, wp, s0 +  96, h, ring, xpa, hv, &sm); ln_phase(s0 +  96, h, hv, gm, bt, ob, &sm);
    conv_phase<16, false>(xb, wp, s0 + 112, h, ring, xpa, hv, &sm); ln_phase(s0 + 112, h, hv, gm, bt, ob, &sm);
}

extern "C" void kernel_launch(void* const* d_in, const int* in_sizes, int n_in,
                              void* d_out, int out_size, void* d_ws, size_t ws_size,
                              hipStream_t stream) {
    const float* x  = (const float*)d_in[0];   // [32, 2048, 512] fp32
    const float* w  = (const float*)d_in[1];   // [1, 64, 512]   fp32
    const float* g  = (const float*)d_in[2];   // [512]
    const float* b  = (const float*)d_in[3];   // [512]
    float* o        = (float*)d_out;           // [32, 2048, 512] fp32

    (void)in_sizes; (void)n_in; (void)out_size; (void)d_ws; (void)ws_size;
    fconv_ln<<<dim3(32 * (S_LEN / S_T)), dim3(HDIM), 0, stream>>>(x, w, g, b, o);
}